// Round 8
// baseline (793.624 us; speedup 1.0000x reference)
//
#include <hip/hip_runtime.h>
#include <hip/hip_bf16.h>

#define SEQ 2048
#define HID 4096
#define NHEADS 32
#define HDIM 128
#define LR 8

typedef __attribute__((ext_vector_type(8))) short bf16x8;
typedef __attribute__((ext_vector_type(4))) float f32x4;
typedef __attribute__((ext_vector_type(16))) float f32x16;

typedef __attribute__((address_space(3))) void lds_void;
typedef const __attribute__((address_space(1))) void glb_void;

static __device__ __forceinline__ float bf2f(__hip_bfloat16 v) { return __bfloat162float(v); }
static __device__ __forceinline__ __hip_bfloat16 f2bf(float v) { return __float2bfloat16(v); }

static __device__ __forceinline__ unsigned pkbf(float lo, float hi2) {
  __hip_bfloat16 l = __float2bfloat16(lo), h2 = __float2bfloat16(hi2);
  unsigned short ul = *reinterpret_cast<unsigned short*>(&l);
  unsigned short uh = *reinterpret_cast<unsigned short*>(&h2);
  return ((unsigned)uh << 16) | ul;
}

// ---------------------------------------------------------------- fp32 -> bf16 (x only now)
__global__ __launch_bounds__(256) void conv_f32_bf16(const float* __restrict__ src,
                                                     __hip_bfloat16* __restrict__ dst,
                                                     int n4) {
  const int i = blockIdx.x * 256 + threadIdx.x;
  if (i >= n4) return;
  const float4 v = reinterpret_cast<const float4*>(src)[i];
  union { __hip_bfloat16 h[4]; ushort4 u; } pk;
  pk.h[0] = f2bf(v.x); pk.h[1] = f2bf(v.y); pk.h[2] = f2bf(v.z); pk.h[3] = f2bf(v.w);
  reinterpret_cast<ushort4*>(dst)[i] = pk.u;
}

// ---------------------------------------------------------------- t = x @ A^T  (fp32, rank 8)
__global__ __launch_bounds__(256) void lora_t(const float* __restrict__ x,
                                              const float* __restrict__ Aq,
                                              const float* __restrict__ Ak,
                                              const float* __restrict__ Av,
                                              float* __restrict__ tq,
                                              float* __restrict__ tk,
                                              float* __restrict__ tv) {
  const int gw = blockIdx.x * 4 + (threadIdx.x >> 6);
  const int lane = threadIdx.x & 63;
  const int which = gw / SEQ;
  const int s = gw - which * SEQ;
  const float* A = (which == 0) ? Aq : (which == 1) ? Ak : Av;
  float* t = (which == 0) ? tq : (which == 1) ? tk : tv;
  float acc[LR];
#pragma unroll
  for (int r = 0; r < LR; ++r) acc[r] = 0.0f;
  const float4* xr = reinterpret_cast<const float4*>(x + (size_t)s * HID);
  for (int c = lane; c < HID / 4; c += 64) {
    const float4 xv = xr[c];
#pragma unroll
    for (int r = 0; r < LR; ++r) {
      const float4 av = reinterpret_cast<const float4*>(A + r * HID)[c];
      acc[r] += xv.x * av.x + xv.y * av.y + xv.z * av.z + xv.w * av.w;
    }
  }
#pragma unroll
  for (int r = 0; r < LR; ++r) {
    float vv = acc[r];
#pragma unroll
    for (int off = 32; off > 0; off >>= 1) vv += __shfl_down(vv, off);
    if (lane == 0) t[s * LR + r] = vv;
  }
}

// ---------------------------------------------------------------- RoPE cos/sin tables [S][64]
__global__ __launch_bounds__(256) void rope_tables(float* __restrict__ cosb,
                                                   float* __restrict__ sinb) {
  const int i = blockIdx.x * 256 + threadIdx.x;
  const int s = i >> 6, d = i & 63;
  const float invf = powf(10000.0f, -(float)d * (1.0f / 64.0f));
  const float ang = (float)s * invf;
  cosb[i] = cosf(ang);
  sinb[i] = sinf(ang);
}

// ---------------------------------------------------------------- RoPE in-place on bf16 (S,4096)
__global__ __launch_bounds__(256) void rope_apply(__hip_bfloat16* __restrict__ t,
                                                  const float* __restrict__ cosb,
                                                  const float* __restrict__ sinb) {
  const int i = blockIdx.x * 256 + threadIdx.x;
  const int d = i & 63;
  const int hh = (i >> 6) & (NHEADS - 1);
  const int s = i >> 11;
  const size_t base = (size_t)s * HID + hh * HDIM;
  const float x1 = bf2f(t[base + d]);
  const float x2 = bf2f(t[base + d + 64]);
  const float cc = cosb[s * 64 + d];
  const float ss = sinb[s * 64 + d];
  t[base + d] = f2bf(x1 * cc - x2 * ss);
  t[base + d + 64] = f2bf(x1 * ss + x2 * cc);
}

// ---------------------------------------------------------------- V (S,4096) -> Vt [h][d][s]
__global__ __launch_bounds__(256) void transpose_v(const __hip_bfloat16* __restrict__ v,
                                                   __hip_bfloat16* __restrict__ vt) {
  __shared__ __hip_bfloat16 tile[64][72];
  const int h = blockIdx.z;
  const int s0 = blockIdx.x * 64;
  const int db = blockIdx.y * 64;
  const int c = (threadIdx.x & 7) * 8;
  const int r = threadIdx.x >> 3;
#pragma unroll
  for (int p = 0; p < 2; ++p) {
    const int rr = r + p * 32;
    *reinterpret_cast<float4*>(&tile[rr][c]) =
        *reinterpret_cast<const float4*>(v + (size_t)(s0 + rr) * HID + h * HDIM + db + c);
  }
  __syncthreads();
#pragma unroll
  for (int p = 0; p < 2; ++p) {
    const int rr = r + p * 32;
    alignas(16) __hip_bfloat16 tmp[8];
#pragma unroll
    for (int j = 0; j < 8; ++j) tmp[j] = tile[c + j][rr];
    *reinterpret_cast<float4*>(vt + (size_t)(h * HDIM + db + rr) * SEQ + s0 + c) =
        *reinterpret_cast<float4*>(tmp);
  }
}

// ---------------------------------------------------------------- counted-vmcnt GEMM, BM=128 BN=256 BK=64
// Fused W fp32->bf16 staging (R8): B loaded as fp32 into regs (8x float4/wave/K-tile,
// issued at kh0 BEFORE the 2 A global_load_lds so they are FIFO-older), converted and
// ds_write_b128'd into swizzled LDS at kh1. vmcnt FIFO invariant per wave:
//   steady state outstanding entering kh0 = 2 (A pair)          -> vmcnt(1)
//   entering kh1 = 11 [A(cur,kh1), B x8, A(nxt) x2]             -> vmcnt(2)
// WAR safe: writes target nxt buffer; all waves passed the last read of that buffer
// via the kh0 barrier. A-path (xb bf16, pre-swizzled global + gload_lds) unchanged.
template <bool LORA>
__global__ __launch_bounds__(512, 2) void gemm2(const __hip_bfloat16* __restrict__ X,
                                                const float* __restrict__ W0,
                                                const float* __restrict__ W1,
                                                const float* __restrict__ W2,
                                                const float* __restrict__ tq,
                                                const float* __restrict__ tk,
                                                const float* __restrict__ tv,
                                                const float* __restrict__ Bq,
                                                const float* __restrict__ Bk,
                                                const float* __restrict__ Bv,
                                                __hip_bfloat16* __restrict__ qb,
                                                __hip_bfloat16* __restrict__ kb,
                                                __hip_bfloat16* __restrict__ vb,
                                                float* __restrict__ outf) {
  __shared__ __hip_bfloat16 Al[2][2][128][32];
  __shared__ __hip_bfloat16 Bl[2][2][256][32];
  const int z = blockIdx.z;
  const float* W = (z == 0) ? W0 : (z == 1) ? W1 : W2;
  const float* T = (z == 0) ? tq : (z == 1) ? tk : tv;
  const float* BL = (z == 0) ? Bq : (z == 1) ? Bk : Bv;
  __hip_bfloat16* outb = (z == 0) ? qb : (z == 1) ? kb : vb;

  const int tid = threadIdx.x;
  const int lane = tid & 63;
  const int w = tid >> 6;   // 0..7
  const int wm = w >> 2;    // 0..1
  const int wn = w & 3;     // 0..3
  const int g = lane >> 4, lr = lane & 15;

  // XCD col-panel swizzle (kept from R7)
  const int fid = blockIdx.x + (blockIdx.y << 4);
  const int xcd = fid & 7;
  const int j8 = fid >> 3;
  const int rowBase = (j8 >> 1) * 128;
  const int colBase = (xcd * 2 + (j8 & 1)) * 256;

  // A staging (bf16, pre-swizzled global source, gload_lds linear dest)
  const int sA = w * 64 + lane;
  const int rA = sA >> 2, cA = sA & 3;
  const __hip_bfloat16* Ag = X + (size_t)(rowBase + rA) * HID + ((cA ^ ((rA >> 1) & 3)) * 8);

  // B staging (fp32 source -> regs -> swizzled ds_write). Slot s = t*64+lane:
  // row = w*32 + (s>>2) (covers 0..255 over 8 waves), chunk cc = s&3 (8 elems).
  const int brow0 = w * 32 + (lane >> 2), bcc0 = lane & 3;
  const int brow1 = w * 32 + 16 + (lane >> 2), bcc1 = lane & 3;
  const float* Bg0 = W + (size_t)(colBase + brow0) * HID + bcc0 * 8;
  const float* Bg1 = W + (size_t)(colBase + brow1) * HID + bcc1 * 8;
  __hip_bfloat16* Bd00 = &Bl[0][0][brow0][(bcc0 ^ ((brow0 >> 1) & 3)) * 8];
  __hip_bfloat16* Bd01 = &Bl[0][0][brow1][(bcc1 ^ ((brow1 >> 1) & 3)) * 8];
  const int khStride = 256 * 32;           // elems between kh planes
  const int bufStride = 2 * 256 * 32;      // elems between dbuf planes (within Bl)

  float4 bld[2][2][2];  // [kh][t][half] -- all statically indexed

#define BLOAD(kk_)                                                                  \
  do {                                                                              \
    _Pragma("unroll") for (int kh_ = 0; kh_ < 2; ++kh_) {                           \
      const float* s0_ = Bg0 + (kk_) + kh_ * 32;                                    \
      const float* s1_ = Bg1 + (kk_) + kh_ * 32;                                    \
      bld[kh_][0][0] = *reinterpret_cast<const float4*>(s0_);                       \
      bld[kh_][0][1] = *reinterpret_cast<const float4*>(s0_ + 4);                   \
      bld[kh_][1][0] = *reinterpret_cast<const float4*>(s1_);                       \
      bld[kh_][1][1] = *reinterpret_cast<const float4*>(s1_ + 4);                   \
    }                                                                               \
  } while (0)

#define BSTORE(buf_)                                                                \
  do {                                                                              \
    _Pragma("unroll") for (int kh_ = 0; kh_ < 2; ++kh_) {                           \
      _Pragma("unroll") for (int t_ = 0; t_ < 2; ++t_) {                            \
        union { __hip_bfloat16 h[8]; bf16x8 v; } pk_;                               \
        pk_.h[0] = f2bf(bld[kh_][t_][0].x); pk_.h[1] = f2bf(bld[kh_][t_][0].y);     \
        pk_.h[2] = f2bf(bld[kh_][t_][0].z); pk_.h[3] = f2bf(bld[kh_][t_][0].w);     \
        pk_.h[4] = f2bf(bld[kh_][t_][1].x); pk_.h[5] = f2bf(bld[kh_][t_][1].y);     \
        pk_.h[6] = f2bf(bld[kh_][t_][1].z); pk_.h[7] = f2bf(bld[kh_][t_][1].w);     \
        __hip_bfloat16* d_ = (t_ == 0 ? Bd00 : Bd01) + (buf_) * bufStride + kh_ * khStride; \
        *reinterpret_cast<bf16x8*>(d_) = pk_.v;                                     \
      }                                                                             \
    }                                                                               \
  } while (0)

#define AGL(buf_, kh_, kk_)                                                         \
  __builtin_amdgcn_global_load_lds((glb_void*)(Ag + (kk_) + (kh_) * 32),            \
      (lds_void*)(&Al[buf_][kh_][0][0] + w * 512), 16, 0, 0)

  f32x4 acc[4][4];
#pragma unroll
  for (int m = 0; m < 4; ++m)
#pragma unroll
    for (int n = 0; n < 4; ++n)
#pragma unroll
      for (int e = 0; e < 4; ++e) acc[m][n][e] = 0.0f;

  const int ch = (g ^ ((lr >> 1) & 3)) * 8;  // swizzled read chunk

  // prologue: B tile0 (regs) first, then A pair -> FIFO [B x8, A x2]
  BLOAD(0);
  AGL(0, 0, 0);
  AGL(0, 1, 0);
  asm volatile("s_waitcnt vmcnt(2)" ::: "memory");  // retire B loads (A pair stays)
  BSTORE(0);

  for (int j = 0; j < 64; ++j) {
    const int cur = j & 1, nxt = cur ^ 1;
    const int kn = (j < 63 ? j + 1 : 63) * 64;  // j==63: redundant re-stage keeps FIFO
    // ---- phase kh0
    asm volatile("s_waitcnt vmcnt(1) lgkmcnt(0)" ::: "memory");
    __builtin_amdgcn_s_barrier();
    __builtin_amdgcn_sched_barrier(0);
    {
      bf16x8 af[4], bfr[4];
#pragma unroll
      for (int m = 0; m < 4; ++m)
        af[m] = *reinterpret_cast<const bf16x8*>(&Al[cur][0][wm * 64 + m * 16 + lr][ch]);
#pragma unroll
      for (int n = 0; n < 4; ++n)
        bfr[n] = *reinterpret_cast<const bf16x8*>(&Bl[cur][0][wn * 64 + n * 16 + lr][ch]);
      BLOAD(kn);
      AGL(nxt, 0, kn);
      AGL(nxt, 1, kn);
      __builtin_amdgcn_sched_barrier(0);
      __builtin_amdgcn_s_setprio(1);
#pragma unroll
      for (int m = 0; m < 4; ++m)
#pragma unroll
        for (int n = 0; n < 4; ++n)
          acc[m][n] = __builtin_amdgcn_mfma_f32_16x16x32_bf16(af[m], bfr[n], acc[m][n], 0, 0, 0);
      __builtin_amdgcn_s_setprio(0);
    }
    // ---- phase kh1
    asm volatile("s_waitcnt vmcnt(2) lgkmcnt(0)" ::: "memory");
    __builtin_amdgcn_s_barrier();
    __builtin_amdgcn_sched_barrier(0);
    {
      bf16x8 af[4], bfr[4];
#pragma unroll
      for (int m = 0; m < 4; ++m)
        af[m] = *reinterpret_cast<const bf16x8*>(&Al[cur][1][wm * 64 + m * 16 + lr][ch]);
#pragma unroll
      for (int n = 0; n < 4; ++n)
        bfr[n] = *reinterpret_cast<const bf16x8*>(&Bl[cur][1][wn * 64 + n * 16 + lr][ch]);
      BSTORE(nxt);
      __builtin_amdgcn_sched_barrier(0);
      __builtin_amdgcn_s_setprio(1);
#pragma unroll
      for (int m = 0; m < 4; ++m)
#pragma unroll
        for (int n = 0; n < 4; ++n)
          acc[m][n] = __builtin_amdgcn_mfma_f32_16x16x32_bf16(af[m], bfr[n], acc[m][n], 0, 0, 0);
      __builtin_amdgcn_s_setprio(0);
    }
  }
#undef BLOAD
#undef BSTORE
#undef AGL

  const int orow0 = rowBase + wm * 64 + g * 4;
  const int ocol0 = colBase + wn * 64 + lr;
  if constexpr (LORA) {
    float bl[4][8];
#pragma unroll
    for (int n = 0; n < 4; ++n) {
      const int cc = ocol0 + n * 16;
      const int fc = (cc < HID / 2) ? (2 * cc) : (2 * (cc - HID / 2) + 1);
#pragma unroll
      for (int e = 0; e < 8; ++e) bl[n][e] = BL[fc * LR + e];
    }
#pragma unroll
    for (int m = 0; m < 4; ++m) {
      float tr[4][8];
#pragma unroll
      for (int r2 = 0; r2 < 4; ++r2)
#pragma unroll
        for (int e = 0; e < 8; ++e) tr[r2][e] = T[(size_t)(orow0 + m * 16 + r2) * LR + e];
#pragma unroll
      for (int n = 0; n < 4; ++n)
#pragma unroll
        for (int r2 = 0; r2 < 4; ++r2) {
          float dot = 0.0f;
#pragma unroll
          for (int e = 0; e < 8; ++e) dot += tr[r2][e] * bl[n][e];
          outb[(size_t)(orow0 + m * 16 + r2) * HID + ocol0 + n * 16] =
              f2bf(acc[m][n][r2] + 2.0f * dot);
        }
    }
  } else {
#pragma unroll
    for (int m = 0; m < 4; ++m)
#pragma unroll
      for (int n = 0; n < 4; ++n)
#pragma unroll
        for (int r2 = 0; r2 < 4; ++r2)
          outf[(size_t)(orow0 + m * 16 + r2) * HID + ocol0 + n * 16] = acc[m][n][r2];
  }
}

// ---------------------------------------------------------------- causal flash attention v4
#define STAGE(buf_, kvb_)                                                                   \
  do {                                                                                      \
    _Pragma("unroll") for (int i_ = 0; i_ < 4; ++i_) {                                      \
      const int sb_ = (w * 4 + i_) * 64;                                                    \
      {                                                                                     \
        const int slot_ = sb_ + lane;                                                       \
        const int rr_ = slot_ >> 4, cc_ = slot_ & 15;                                       \
        __builtin_amdgcn_global_load_lds(                                                   \
            (glb_void*)(kg + (size_t)((kvb_) + rr_) * HID + h * HDIM +                      \
                        ((cc_ ^ (rr_ & 15)) << 3)),                                         \
            (lds_void*)(&Ks[buf_][sb_ * 8]), 16, 0, 0);                                     \
      }                                                                                     \
      {                                                                                     \
        const int slot_ = sb_ + lane;                                                       \
        const int rr_ = slot_ >> 3, cc_ = slot_ & 7;                                        \
        __builtin_amdgcn_global_load_lds(                                                   \
            (glb_void*)(vt + ((size_t)h * HDIM + rr_) * SEQ + (kvb_) +                      \
                        ((cc_ ^ (rr_ & 7)) << 3)),                                          \
            (lds_void*)(&Vs[buf_][sb_ * 8]), 16, 0, 0);                                     \
      }                                                                                     \
    }                                                                                       \
  } while (0)

__global__ __launch_bounds__(256, 2) void flash_attn4(const __hip_bfloat16* __restrict__ qg,
                                                      const __hip_bfloat16* __restrict__ kg,
                                                      const __hip_bfloat16* __restrict__ vt,
                                                      __hip_bfloat16* __restrict__ o) {
  __shared__ __hip_bfloat16 Ks[2][64 * 128];  // [kv][d], chunk ^= (row&15)
  __shared__ __hip_bfloat16 Vs[2][128 * 64];  // [d][kv], chunk ^= (row&7)
  const int tid = threadIdx.x;
  const int lane = tid & 63;
  const int w = tid >> 6;
  const int ql = lane & 31;
  const int hi = lane >> 5;
  const int bx = blockIdx.x;
  const int h = bx & 31;
  const int strip = (bx < 256) ? (bx >> 5) : (15 - ((bx - 256) >> 5));
  const float scale = 0.088388347648318447f;  // 1/sqrt(128)

  const int q0 = strip * 128 + w * 32;
  const int nt = 2 * strip + 2;
  const int qgl = q0 + ql;

  bf16x8 bq[8];
#pragma unroll
  for (int sl = 0; sl < 8; ++sl)
    bq[sl] = *reinterpret_cast<const bf16x8*>(qg + (size_t)qgl * HID + h * HDIM + sl * 16 + hi * 8);

  f32x16 accO[4];
#pragma unroll
  for (int db = 0; db < 4; ++db)
#pragma unroll
    for (int e = 0; e < 16; ++e) accO[db][e] = 0.0f;
  float m_run = -1e30f, lsum = 0.0f;

  int cur = 0;
  STAGE(0, 0);
  asm volatile("s_waitcnt vmcnt(0)");
  __syncthreads();

  for (int t = 0; t < nt; ++t) {
    const int kvb = t * 64;
    if (t + 1 < nt) STAGE(cur ^ 1, (t + 1) * 64);
    if (kvb <= q0 + 31) {
      f32x16 sc[2];
#pragma unroll
      for (int sub = 0; sub < 2; ++sub) {
#pragma unroll
        for (int e = 0; e < 16; ++e) sc[sub][e] = 0.0f;
        const int krow = sub * 32 + ql;
#pragma unroll
        for (int sl = 0; sl < 8; ++sl) {
          const int chh = (sl * 2 + hi) ^ (ql & 15);
          bf16x8 ak = *reinterpret_cast<const bf16x8*>(&Ks[cur][krow * 128 + chh * 8]);
          sc[sub] = __builtin_amdgcn_mfma_f32_32x32x16_bf16(ak, bq[sl], sc[sub], 0, 0, 0);
        }
      }
      float smax = -3.0e38f;
      if (kvb + 63 > q0) {
#pragma unroll
        for (int sub = 0; sub < 2; ++sub)
#pragma unroll
          for (int r = 0; r < 16; ++r) {
            const int kvg = kvb + sub * 32 + (r & 3) + 8 * (r >> 2) + 4 * hi;
            float v2 = sc[sub][r] * scale;
            v2 = (kvg > qgl) ? -3.0e38f : v2;
            sc[sub][r] = v2;
            smax = fmaxf(smax, v2);
          }
      } else {
#pragma unroll
        for (int sub = 0; sub < 2; ++sub)
#pragma unroll
          for (int r = 0; r < 16; ++r) {
            const float v2 = sc[sub][r] * scale;
            sc[sub][r] = v2;
            smax = fmaxf(smax, v2);
          }
      }
      smax = fmaxf(smax, __shfl_xor(smax, 32));
      if (__any(smax > m_run + 8.0f)) {
        const float mnew = fmaxf(m_run, smax);
        const float sca = __expf(m_run - mnew);
        m_run = mnew;
        lsum *= sca;
#pragma unroll
        for (int r = 0; r < 16; ++r) {
          const float sr = __shfl(sca, (r & 3) + 8 * (r >> 2) + 4 * hi);
#pragma unroll
          for (int db = 0; db < 4; ++db) accO[db][r] *= sr;
        }
      }
      float psum = 0.0f;
#pragma unroll
      for (int sub = 0; sub < 2; ++sub)
#pragma unroll
        for (int r = 0; r < 16; ++r) {
          const float p = __expf(sc[sub][r] - m_run);
          sc[sub][r] = p;
          psum += p;
        }
      psum += __shfl_xor(psum, 32);
      lsum += psum;
      bf16x8 pa[4];
#pragma unroll
      for (int sub = 0; sub < 2; ++sub) {
        const unsigned A0 = pkbf(sc[sub][0], sc[sub][1]);
        const unsigned C0 = pkbf(sc[sub][2], sc[sub][3]);
        const unsigned B0 = pkbf(sc[sub][4], sc[sub][5]);
        const unsigned D0 = pkbf(sc[sub][6], sc[sub][7]);
        const unsigned A1 = pkbf(sc[sub][8], sc[sub][9]);
        const unsigned C1 = pkbf(sc[sub][10], sc[sub][11]);
        const unsigned B1 = pkbf(sc[sub][12], sc[sub][13]);
        const unsigned D1 = pkbf(sc[sub][14], sc[sub][15]);
        const unsigned sA0 = (unsigned)__shfl_xor((int)A0, 32);
        const unsigned sB0 = (unsigned)__shfl_xor((int)B0, 32);
        const unsigned sC0 = (unsigned)__shfl_xor((int)C0, 32);
        const unsigned sD0 = (unsigned)__shfl_xor((int)D0, 32);
        const unsigned sA1 = (unsigned)__shfl_xor((int)A1, 32);
        const unsigned sB1 = (unsigned)__shfl_xor((int)B1, 32);
        const unsigned sC1 = (unsigned)__shfl_xor((int)C1, 32);
        const unsigned sD1 = (unsigned)__shfl_xor((int)D1, 32);
        union { unsigned u[4]; bf16x8 v; } f0, f1;
        f0.u[0] = hi ? sB0 : A0;
        f0.u[1] = hi ? sD0 : C0;
        f0.u[2] = hi ? B0 : sA0;
        f0.u[3] = hi ? D0 : sC0;
        f1.u[0] = hi ? sB1 : A1;
        f1.u[1] = hi ? sD1 : C1;
        f1.u[2] = hi ? B1 : sA1;
        f1.u[3] = hi ? D1 : sC1;
        pa[sub * 2 + 0] = f0.v;
        pa[sub * 2 + 1] = f1.v;
      }
#pragma unroll
      for (int db = 0; db < 4; ++db) {
        const int vrow = db * 32 + ql;
#pragma unroll
        for (int ks = 0; ks < 4; ++ks) {
          const int chh = (ks * 2 + hi) ^ (ql & 7);
          bf16x8 bv = *reinterpret_cast<const bf16x8*>(&Vs[cur][vrow * 64 + chh * 8]);
          accO[db] = __builtin_amdgcn_mfma_f32_32x32x16_bf16(pa[ks], bv, accO[db], 0, 0, 0);
        }
      }
    }
    asm volatile("s_waitcnt vmcnt(0)");
    __syncthreads();
    cur ^= 1;
  }
  const float il = 1.0f / lsum;
#pragma unroll
  for (int r = 0; r < 16; ++r) {
    const int rb = (r & 3) + 8 * (r >> 2);
    const float ir = __shfl(il, rb + 4 * hi);
    const int qrow = q0 + rb + 4 * hi;
#pragma unroll
    for (int db = 0; db < 4; ++db)
      o[(size_t)qrow * HID + h * HDIM + db * 32 + ql] = f2bf(accO[db][r] * ir);
  }
}

// ----------------------------------------------------------------
extern "C" void kernel_launch(void* const* d_in, const int* in_sizes, int n_in,
                              void* d_out, int out_size, void* d_ws, size_t ws_size,
                              hipStream_t stream) {
  (void)in_sizes; (void)n_in; (void)out_size; (void)ws_size;
  const float* x  = (const float*)d_in[0];
  const float* Wq = (const float*)d_in[1];
  const float* Wk = (const float*)d_in[2];
  const float* Wv = (const float*)d_in[3];
  const float* Wo = (const float*)d_in[4];
  const float* Aq = (const float*)d_in[5];
  const float* Bq = (const float*)d_in[6];
  const float* Ak = (const float*)d_in[7];
  const float* Bk = (const float*)d_in[8];
  const float* Av = (const float*)d_in[9];
  const float* Bv = (const float*)d_in[10];
  float* out = (float*)d_out;

  char* p = (char*)d_ws;
  __hip_bfloat16* xb   = (__hip_bfloat16*)p; p += (size_t)SEQ * HID * 2;  // reused as ab
  __hip_bfloat16* qb   = (__hip_bfloat16*)p; p += (size_t)SEQ * HID * 2;
  __hip_bfloat16* kb   = (__hip_bfloat16*)p; p += (size_t)SEQ * HID * 2;
  __hip_bfloat16* vb   = (__hip_bfloat16*)p; p += (size_t)SEQ * HID * 2;
  __hip_bfloat16* vtb  = (__hip_bfloat16*)p; p += (size_t)SEQ * HID * 2;
  float* tq   = (float*)p; p += SEQ * LR * 4;
  float* tk   = (float*)p; p += SEQ * LR * 4;
  float* tv   = (float*)p; p += SEQ * LR * 4;
  float* cosb = (float*)p; p += SEQ * 64 * 4;
  float* sinb = (float*)p; p += SEQ * 64 * 4;
  __hip_bfloat16* ab = xb;  // x no longer needed after QKV GEMMs

  conv_f32_bf16<<<SEQ * HID / 1024, 256, 0, stream>>>(x, xb, SEQ * HID / 4);
  lora_t<<<SEQ * 3 / 4, 256, 0, stream>>>(x, Aq, Ak, Av, tq, tk, tv);
  rope_tables<<<SEQ * 64 / 256, 256, 0, stream>>>(cosb, sinb);

  gemm2<true><<<dim3(16, 16, 3), 512, 0, stream>>>(xb, Wq, Wk, Wv, tq, tk, tv, Bq, Bk, Bv,
                                                   qb, kb, vb, nullptr);

  rope_apply<<<SEQ * NHEADS * 64 / 256, 256, 0, stream>>>(qb, cosb, sinb);
  rope_apply<<<SEQ * NHEADS * 64 / 256, 256, 0, stream>>>(kb, cosb, sinb);
  transpose_v<<<dim3(SEQ / 64, HDIM / 64, NHEADS), 256, 0, stream>>>(vb, vtb);
  flash_attn4<<<512, 256, 0, stream>>>(qb, kb, vtb, ab);

  gemm2<false><<<dim3(16, 16, 1), 512, 0, stream>>>(ab, Wo, Wo, Wo, nullptr, nullptr, nullptr,
                                                    nullptr, nullptr, nullptr,
                                                    nullptr, nullptr, nullptr, out);
}

// Round 9
// 575.174 us; speedup vs baseline: 1.3798x; 1.3798x over previous
//
#include <hip/hip_runtime.h>
#include <hip/hip_bf16.h>

#define SEQ 2048
#define HID 4096
#define NHEADS 32
#define HDIM 128
#define LR 8

typedef __attribute__((ext_vector_type(8))) short bf16x8;
typedef __attribute__((ext_vector_type(4))) float f32x4;
typedef __attribute__((ext_vector_type(16))) float f32x16;

typedef __attribute__((address_space(3))) void lds_void;
typedef const __attribute__((address_space(1))) void glb_void;

static __device__ __forceinline__ float bf2f(__hip_bfloat16 v) { return __bfloat162float(v); }
static __device__ __forceinline__ __hip_bfloat16 f2bf(float v) { return __float2bfloat16(v); }

static __device__ __forceinline__ unsigned pkbf(float lo, float hi2) {
  __hip_bfloat16 l = __float2bfloat16(lo), h2 = __float2bfloat16(hi2);
  unsigned short ul = *reinterpret_cast<unsigned short*>(&l);
  unsigned short uh = *reinterpret_cast<unsigned short*>(&h2);
  return ((unsigned)uh << 16) | ul;
}

// ---------------------------------------------------------------- fp32 -> bf16
__global__ __launch_bounds__(256) void conv_f32_bf16(const float* __restrict__ src,
                                                     __hip_bfloat16* __restrict__ dst,
                                                     int n4) {
  const int i = blockIdx.x * 256 + threadIdx.x;
  if (i >= n4) return;
  const float4 v = reinterpret_cast<const float4*>(src)[i];
  union { __hip_bfloat16 h[4]; ushort4 u; } pk;
  pk.h[0] = f2bf(v.x); pk.h[1] = f2bf(v.y); pk.h[2] = f2bf(v.z); pk.h[3] = f2bf(v.w);
  reinterpret_cast<ushort4*>(dst)[i] = pk.u;
}

// ---------------------------------------------------------------- t = x @ A^T  (fp32, rank 8)
__global__ __launch_bounds__(256) void lora_t(const float* __restrict__ x,
                                              const float* __restrict__ Aq,
                                              const float* __restrict__ Ak,
                                              const float* __restrict__ Av,
                                              float* __restrict__ tq,
                                              float* __restrict__ tk,
                                              float* __restrict__ tv) {
  const int gw = blockIdx.x * 4 + (threadIdx.x >> 6);
  const int lane = threadIdx.x & 63;
  const int which = gw / SEQ;
  const int s = gw - which * SEQ;
  const float* A = (which == 0) ? Aq : (which == 1) ? Ak : Av;
  float* t = (which == 0) ? tq : (which == 1) ? tk : tv;
  float acc[LR];
#pragma unroll
  for (int r = 0; r < LR; ++r) acc[r] = 0.0f;
  const float4* xr = reinterpret_cast<const float4*>(x + (size_t)s * HID);
  for (int c = lane; c < HID / 4; c += 64) {
    const float4 xv = xr[c];
#pragma unroll
    for (int r = 0; r < LR; ++r) {
      const float4 av = reinterpret_cast<const float4*>(A + r * HID)[c];
      acc[r] += xv.x * av.x + xv.y * av.y + xv.z * av.z + xv.w * av.w;
    }
  }
#pragma unroll
  for (int r = 0; r < LR; ++r) {
    float vv = acc[r];
#pragma unroll
    for (int off = 32; off > 0; off >>= 1) vv += __shfl_down(vv, off);
    if (lane == 0) t[s * LR + r] = vv;
  }
}

// ---------------------------------------------------------------- RoPE cos/sin tables [S][64]
__global__ __launch_bounds__(256) void rope_tables(float* __restrict__ cosb,
                                                   float* __restrict__ sinb) {
  const int i = blockIdx.x * 256 + threadIdx.x;
  const int s = i >> 6, d = i & 63;
  const float invf = powf(10000.0f, -(float)d * (1.0f / 64.0f));
  const float ang = (float)s * invf;
  cosb[i] = cosf(ang);
  sinb[i] = sinf(ang);
}

// ---------------------------------------------------------------- RoPE in-place on bf16 (S,4096)
__global__ __launch_bounds__(256) void rope_apply(__hip_bfloat16* __restrict__ t,
                                                  const float* __restrict__ cosb,
                                                  const float* __restrict__ sinb) {
  const int i = blockIdx.x * 256 + threadIdx.x;
  const int d = i & 63;
  const int hh = (i >> 6) & (NHEADS - 1);
  const int s = i >> 11;
  const size_t base = (size_t)s * HID + hh * HDIM;
  const float x1 = bf2f(t[base + d]);
  const float x2 = bf2f(t[base + d + 64]);
  const float cc = cosb[s * 64 + d];
  const float ss = sinb[s * 64 + d];
  t[base + d] = f2bf(x1 * cc - x2 * ss);
  t[base + d + 64] = f2bf(x1 * ss + x2 * cc);
}

// ---------------------------------------------------------------- V (S,4096) -> Vt [h][d][s]
__global__ __launch_bounds__(256) void transpose_v(const __hip_bfloat16* __restrict__ v,
                                                   __hip_bfloat16* __restrict__ vt) {
  __shared__ __hip_bfloat16 tile[64][72];
  const int h = blockIdx.z;
  const int s0 = blockIdx.x * 64;
  const int db = blockIdx.y * 64;
  const int c = (threadIdx.x & 7) * 8;
  const int r = threadIdx.x >> 3;
#pragma unroll
  for (int p = 0; p < 2; ++p) {
    const int rr = r + p * 32;
    *reinterpret_cast<float4*>(&tile[rr][c]) =
        *reinterpret_cast<const float4*>(v + (size_t)(s0 + rr) * HID + h * HDIM + db + c);
  }
  __syncthreads();
#pragma unroll
  for (int p = 0; p < 2; ++p) {
    const int rr = r + p * 32;
    alignas(16) __hip_bfloat16 tmp[8];
#pragma unroll
    for (int j = 0; j < 8; ++j) tmp[j] = tile[c + j][rr];
    *reinterpret_cast<float4*>(vt + (size_t)(h * HDIM + db + rr) * SEQ + s0 + c) =
        *reinterpret_cast<float4*>(tmp);
  }
}

// ---------------------------------------------------------------- QKV GEMM v3: BM=256 BN=256 BK=64
// 8 waves, wave output 64x128 = 4x8 frags -> 12 ds_read_b128 per 32 MFMA (0.375 vs
// R7's 0.5): attacks the measured LDS-BW bound. Same verified R7 loop structure:
// counted vmcnt (4 loads/phase, 8 outstanding, vmcnt(4) retires the kh being read),
// T2 both-sides swizzle, XCD col-panel L2 mapping. LDS 128KB -> 1 block/CU.
template <bool LORA>
__global__ __launch_bounds__(512, 2) void gemm3(const __hip_bfloat16* __restrict__ X,
                                                const __hip_bfloat16* __restrict__ wqkv,
                                                const float* __restrict__ tq,
                                                const float* __restrict__ tk,
                                                const float* __restrict__ tv,
                                                const float* __restrict__ Bq,
                                                const float* __restrict__ Bk,
                                                const float* __restrict__ Bv,
                                                __hip_bfloat16* __restrict__ qb,
                                                __hip_bfloat16* __restrict__ kb,
                                                __hip_bfloat16* __restrict__ vb,
                                                float* __restrict__ outf) {
  __shared__ __hip_bfloat16 Al[2][2][256][32];  // 64 KB
  __shared__ __hip_bfloat16 Bl[2][2][256][32];  // 64 KB
  const int z = blockIdx.z;
  const __hip_bfloat16* W = wqkv + (size_t)z * HID * HID;
  const float* T = (z == 0) ? tq : (z == 1) ? tk : tv;
  const float* BL = (z == 0) ? Bq : (z == 1) ? Bk : Bv;
  __hip_bfloat16* outb = (z == 0) ? qb : (z == 1) ? kb : vb;

  const int tid = threadIdx.x;
  const int lane = tid & 63;
  const int w = tid >> 6;   // 0..7
  const int wm = w & 3;     // M quadrant (64 rows)
  const int wn = w >> 2;    // N half (128 cols)
  const int g = lane >> 4, lr = lane & 15;

  // XCD col-panel swizzle: xcd owns col panels {2x, 2x+1} = 4MB of W (L2-resident)
  const int fid = blockIdx.x + (blockIdx.y << 4);  // bx 0..15, by 0..7
  const int xcd = fid & 7;
  const int j8 = fid >> 3;                         // 0..15
  const int rowBase = (j8 >> 1) * 256;             // 0..7 row panels
  const int colBase = (xcd * 2 + (j8 & 1)) * 256;  // 0..15 col panels

  // staging: per kh plane 256x32 bf16 = 1024 16B slots; 8 waves x 2 loads each
  const int s0 = (w * 2) * 64 + lane;
  const int s1 = (w * 2 + 1) * 64 + lane;
  const int r0 = s0 >> 2, c0 = s0 & 3;
  const int r1 = s1 >> 2, c1 = s1 & 3;
  const __hip_bfloat16* Ag0 = X + (size_t)(rowBase + r0) * HID + ((c0 ^ ((r0 >> 1) & 3)) * 8);
  const __hip_bfloat16* Ag1 = X + (size_t)(rowBase + r1) * HID + ((c1 ^ ((r1 >> 1) & 3)) * 8);
  const __hip_bfloat16* Bg0 = W + (size_t)(colBase + r0) * HID + ((c0 ^ ((r0 >> 1) & 3)) * 8);
  const __hip_bfloat16* Bg1 = W + (size_t)(colBase + r1) * HID + ((c1 ^ ((r1 >> 1) & 3)) * 8);

#define STG3(buf_, kh_, kk_)                                                        \
  do {                                                                              \
    __builtin_amdgcn_global_load_lds((glb_void*)(Ag0 + (kk_) + (kh_) * 32),         \
        (lds_void*)(&Al[buf_][kh_][0][0] + (w * 2) * 512), 16, 0, 0);               \
    __builtin_amdgcn_global_load_lds((glb_void*)(Ag1 + (kk_) + (kh_) * 32),         \
        (lds_void*)(&Al[buf_][kh_][0][0] + (w * 2 + 1) * 512), 16, 0, 0);           \
    __builtin_amdgcn_global_load_lds((glb_void*)(Bg0 + (kk_) + (kh_) * 32),         \
        (lds_void*)(&Bl[buf_][kh_][0][0] + (w * 2) * 512), 16, 0, 0);               \
    __builtin_amdgcn_global_load_lds((glb_void*)(Bg1 + (kk_) + (kh_) * 32),         \
        (lds_void*)(&Bl[buf_][kh_][0][0] + (w * 2 + 1) * 512), 16, 0, 0);           \
  } while (0)

  f32x4 acc[4][8];
#pragma unroll
  for (int m = 0; m < 4; ++m)
#pragma unroll
    for (int n = 0; n < 8; ++n)
#pragma unroll
      for (int e = 0; e < 4; ++e) acc[m][n][e] = 0.0f;

  const int ch = (g ^ ((lr >> 1) & 3)) * 8;  // swizzled read chunk

  STG3(0, 0, 0);
  __builtin_amdgcn_sched_barrier(0);
  STG3(0, 1, 0);

  for (int j = 0; j < 64; ++j) {
    const int cur = j & 1, nxt = cur ^ 1;
    const int kn = (j < 63 ? j + 1 : 63) * 64;  // j==63: redundant re-stage keeps FIFO
#pragma unroll
    for (int kh = 0; kh < 2; ++kh) {
      asm volatile("s_waitcnt vmcnt(4) lgkmcnt(0)" ::: "memory");
      __builtin_amdgcn_s_barrier();
      __builtin_amdgcn_sched_barrier(0);
      bf16x8 af[4], bfr[8];
#pragma unroll
      for (int m = 0; m < 4; ++m)
        af[m] = *reinterpret_cast<const bf16x8*>(&Al[cur][kh][wm * 64 + m * 16 + lr][ch]);
#pragma unroll
      for (int n = 0; n < 8; ++n)
        bfr[n] = *reinterpret_cast<const bf16x8*>(&Bl[cur][kh][wn * 128 + n * 16 + lr][ch]);
      if (kh == 0) STG3(nxt, 0, kn); else STG3(nxt, 1, kn);
      __builtin_amdgcn_sched_barrier(0);
      __builtin_amdgcn_s_setprio(1);
#pragma unroll
      for (int m = 0; m < 4; ++m)
#pragma unroll
        for (int n = 0; n < 8; ++n)
          acc[m][n] = __builtin_amdgcn_mfma_f32_16x16x32_bf16(af[m], bfr[n], acc[m][n], 0, 0, 0);
      __builtin_amdgcn_s_setprio(0);
    }
  }
#undef STG3

  const int orow0 = rowBase + wm * 64 + g * 4;
  const int ocol0 = colBase + wn * 128 + lr;
  if constexpr (LORA) {
#pragma unroll
    for (int m = 0; m < 4; ++m) {
      float tr[4][8];
#pragma unroll
      for (int r2 = 0; r2 < 4; ++r2)
#pragma unroll
        for (int e = 0; e < 8; ++e) tr[r2][e] = T[(size_t)(orow0 + m * 16 + r2) * LR + e];
#pragma unroll
      for (int n = 0; n < 8; ++n) {
        const int cc = ocol0 + n * 16;
        const int fc = (cc < HID / 2) ? (2 * cc) : (2 * (cc - HID / 2) + 1);
        float bl[8];
#pragma unroll
        for (int e = 0; e < 8; ++e) bl[e] = BL[fc * LR + e];
#pragma unroll
        for (int r2 = 0; r2 < 4; ++r2) {
          float dot = 0.0f;
#pragma unroll
          for (int e = 0; e < 8; ++e) dot += tr[r2][e] * bl[e];
          outb[(size_t)(orow0 + m * 16 + r2) * HID + cc] = f2bf(acc[m][n][r2] + 2.0f * dot);
        }
      }
    }
  } else {
#pragma unroll
    for (int m = 0; m < 4; ++m)
#pragma unroll
      for (int n = 0; n < 8; ++n)
#pragma unroll
        for (int r2 = 0; r2 < 4; ++r2)
          outf[(size_t)(orow0 + m * 16 + r2) * HID + ocol0 + n * 16] = acc[m][n][r2];
  }
}

// ---------------------------------------------------------------- Wo GEMM (R7 verified), BM=128 BN=256
__global__ __launch_bounds__(512, 2) void gemm2o(const __hip_bfloat16* __restrict__ X,
                                                 const __hip_bfloat16* __restrict__ W,
                                                 float* __restrict__ outf) {
  __shared__ __hip_bfloat16 Al[2][2][128][32];
  __shared__ __hip_bfloat16 Bl[2][2][256][32];
  const int tid = threadIdx.x;
  const int lane = tid & 63;
  const int w = tid >> 6;
  const int wm = w >> 2;
  const int wn = w & 3;
  const int g = lane >> 4, lr = lane & 15;

  const int fid = blockIdx.x + (blockIdx.y << 4);
  const int xcd = fid & 7;
  const int j8 = fid >> 3;
  const int rowBase = (j8 >> 1) * 128;
  const int colBase = (xcd * 2 + (j8 & 1)) * 256;

  const int sA = w * 64 + lane;
  const int rA = sA >> 2, cA = sA & 3;
  const __hip_bfloat16* Ag = X + (size_t)(rowBase + rA) * HID + ((cA ^ ((rA >> 1) & 3)) * 8);
  const int sB0 = (w * 2) * 64 + lane;
  const int sB1 = (w * 2 + 1) * 64 + lane;
  const int rB0 = sB0 >> 2, cB0 = sB0 & 3;
  const int rB1 = sB1 >> 2, cB1 = sB1 & 3;
  const __hip_bfloat16* Bg0 = W + (size_t)(colBase + rB0) * HID + ((cB0 ^ ((rB0 >> 1) & 3)) * 8);
  const __hip_bfloat16* Bg1 = W + (size_t)(colBase + rB1) * HID + ((cB1 ^ ((rB1 >> 1) & 3)) * 8);

#define STG2(buf_, kh_, kk_)                                                        \
  do {                                                                              \
    __builtin_amdgcn_global_load_lds((glb_void*)(Ag + (kk_) + (kh_) * 32),          \
        (lds_void*)(&Al[buf_][kh_][0][0] + w * 512), 16, 0, 0);                     \
    __builtin_amdgcn_global_load_lds((glb_void*)(Bg0 + (kk_) + (kh_) * 32),         \
        (lds_void*)(&Bl[buf_][kh_][0][0] + (w * 2) * 512), 16, 0, 0);               \
    __builtin_amdgcn_global_load_lds((glb_void*)(Bg1 + (kk_) + (kh_) * 32),         \
        (lds_void*)(&Bl[buf_][kh_][0][0] + (w * 2 + 1) * 512), 16, 0, 0);           \
  } while (0)

  f32x4 acc[4][4];
#pragma unroll
  for (int m = 0; m < 4; ++m)
#pragma unroll
    for (int n = 0; n < 4; ++n)
#pragma unroll
      for (int e = 0; e < 4; ++e) acc[m][n][e] = 0.0f;

  const int ch = (g ^ ((lr >> 1) & 3)) * 8;

  STG2(0, 0, 0);
  __builtin_amdgcn_sched_barrier(0);
  STG2(0, 1, 0);

  for (int j = 0; j < 64; ++j) {
    const int cur = j & 1, nxt = cur ^ 1;
    const int kn = (j < 63 ? j + 1 : 63) * 64;
#pragma unroll
    for (int kh = 0; kh < 2; ++kh) {
      asm volatile("s_waitcnt vmcnt(3) lgkmcnt(0)" ::: "memory");
      __builtin_amdgcn_s_barrier();
      __builtin_amdgcn_sched_barrier(0);
      bf16x8 af[4], bfr[4];
#pragma unroll
      for (int m = 0; m < 4; ++m)
        af[m] = *reinterpret_cast<const bf16x8*>(&Al[cur][kh][wm * 64 + m * 16 + lr][ch]);
#pragma unroll
      for (int n = 0; n < 4; ++n)
        bfr[n] = *reinterpret_cast<const bf16x8*>(&Bl[cur][kh][wn * 64 + n * 16 + lr][ch]);
      if (kh == 0) STG2(nxt, 0, kn); else STG2(nxt, 1, kn);
      __builtin_amdgcn_sched_barrier(0);
      __builtin_amdgcn_s_setprio(1);
#pragma unroll
      for (int m = 0; m < 4; ++m)
#pragma unroll
        for (int n = 0; n < 4; ++n)
          acc[m][n] = __builtin_amdgcn_mfma_f32_16x16x32_bf16(af[m], bfr[n], acc[m][n], 0, 0, 0);
      __builtin_amdgcn_s_setprio(0);
    }
  }
#undef STG2

  const int orow0 = rowBase + wm * 64 + g * 4;
  const int ocol0 = colBase + wn * 64 + lr;
#pragma unroll
  for (int m = 0; m < 4; ++m)
#pragma unroll
    for (int n = 0; n < 4; ++n)
#pragma unroll
      for (int r2 = 0; r2 < 4; ++r2)
        outf[(size_t)(orow0 + m * 16 + r2) * HID + ocol0 + n * 16] = acc[m][n][r2];
}

// ---------------------------------------------------------------- causal flash attention v4
#define STAGE(buf_, kvb_)                                                                   \
  do {                                                                                      \
    _Pragma("unroll") for (int i_ = 0; i_ < 4; ++i_) {                                      \
      const int sb_ = (w * 4 + i_) * 64;                                                    \
      {                                                                                     \
        const int slot_ = sb_ + lane;                                                       \
        const int rr_ = slot_ >> 4, cc_ = slot_ & 15;                                       \
        __builtin_amdgcn_global_load_lds(                                                   \
            (glb_void*)(kg + (size_t)((kvb_) + rr_) * HID + h * HDIM +                      \
                        ((cc_ ^ (rr_ & 15)) << 3)),                                         \
            (lds_void*)(&Ks[buf_][sb_ * 8]), 16, 0, 0);                                     \
      }                                                                                     \
      {                                                                                     \
        const int slot_ = sb_ + lane;                                                       \
        const int rr_ = slot_ >> 3, cc_ = slot_ & 7;                                        \
        __builtin_amdgcn_global_load_lds(                                                   \
            (glb_void*)(vt + ((size_t)h * HDIM + rr_) * SEQ + (kvb_) +                      \
                        ((cc_ ^ (rr_ & 7)) << 3)),                                          \
            (lds_void*)(&Vs[buf_][sb_ * 8]), 16, 0, 0);                                     \
      }                                                                                     \
    }                                                                                       \
  } while (0)

__global__ __launch_bounds__(256, 2) void flash_attn4(const __hip_bfloat16* __restrict__ qg,
                                                      const __hip_bfloat16* __restrict__ kg,
                                                      const __hip_bfloat16* __restrict__ vt,
                                                      __hip_bfloat16* __restrict__ o) {
  __shared__ __hip_bfloat16 Ks[2][64 * 128];
  __shared__ __hip_bfloat16 Vs[2][128 * 64];
  const int tid = threadIdx.x;
  const int lane = tid & 63;
  const int w = tid >> 6;
  const int ql = lane & 31;
  const int hi = lane >> 5;
  const int bx = blockIdx.x;
  const int h = bx & 31;
  const int strip = (bx < 256) ? (bx >> 5) : (15 - ((bx - 256) >> 5));
  const float scale = 0.088388347648318447f;

  const int q0 = strip * 128 + w * 32;
  const int nt = 2 * strip + 2;
  const int qgl = q0 + ql;

  bf16x8 bq[8];
#pragma unroll
  for (int sl = 0; sl < 8; ++sl)
    bq[sl] = *reinterpret_cast<const bf16x8*>(qg + (size_t)qgl * HID + h * HDIM + sl * 16 + hi * 8);

  f32x16 accO[4];
#pragma unroll
  for (int db = 0; db < 4; ++db)
#pragma unroll
    for (int e = 0; e < 16; ++e) accO[db][e] = 0.0f;
  float m_run = -1e30f, lsum = 0.0f;

  int cur = 0;
  STAGE(0, 0);
  asm volatile("s_waitcnt vmcnt(0)");
  __syncthreads();

  for (int t = 0; t < nt; ++t) {
    const int kvb = t * 64;
    if (t + 1 < nt) STAGE(cur ^ 1, (t + 1) * 64);
    if (kvb <= q0 + 31) {
      f32x16 sc[2];
#pragma unroll
      for (int sub = 0; sub < 2; ++sub) {
#pragma unroll
        for (int e = 0; e < 16; ++e) sc[sub][e] = 0.0f;
        const int krow = sub * 32 + ql;
#pragma unroll
        for (int sl = 0; sl < 8; ++sl) {
          const int chh = (sl * 2 + hi) ^ (ql & 15);
          bf16x8 ak = *reinterpret_cast<const bf16x8*>(&Ks[cur][krow * 128 + chh * 8]);
          sc[sub] = __builtin_amdgcn_mfma_f32_32x32x16_bf16(ak, bq[sl], sc[sub], 0, 0, 0);
        }
      }
      float smax = -3.0e38f;
      if (kvb + 63 > q0) {
#pragma unroll
        for (int sub = 0; sub < 2; ++sub)
#pragma unroll
          for (int r = 0; r < 16; ++r) {
            const int kvg = kvb + sub * 32 + (r & 3) + 8 * (r >> 2) + 4 * hi;
            float v2 = sc[sub][r] * scale;
            v2 = (kvg > qgl) ? -3.0e38f : v2;
            sc[sub][r] = v2;
            smax = fmaxf(smax, v2);
          }
      } else {
#pragma unroll
        for (int sub = 0; sub < 2; ++sub)
#pragma unroll
          for (int r = 0; r < 16; ++r) {
            const float v2 = sc[sub][r] * scale;
            sc[sub][r] = v2;
            smax = fmaxf(smax, v2);
          }
      }
      smax = fmaxf(smax, __shfl_xor(smax, 32));
      if (__any(smax > m_run + 8.0f)) {
        const float mnew = fmaxf(m_run, smax);
        const float sca = __expf(m_run - mnew);
        m_run = mnew;
        lsum *= sca;
#pragma unroll
        for (int r = 0; r < 16; ++r) {
          const float sr = __shfl(sca, (r & 3) + 8 * (r >> 2) + 4 * hi);
#pragma unroll
          for (int db = 0; db < 4; ++db) accO[db][r] *= sr;
        }
      }
      float psum = 0.0f;
#pragma unroll
      for (int sub = 0; sub < 2; ++sub)
#pragma unroll
        for (int r = 0; r < 16; ++r) {
          const float p = __expf(sc[sub][r] - m_run);
          sc[sub][r] = p;
          psum += p;
        }
      psum += __shfl_xor(psum, 32);
      lsum += psum;
      bf16x8 pa[4];
#pragma unroll
      for (int sub = 0; sub < 2; ++sub) {
        const unsigned A0 = pkbf(sc[sub][0], sc[sub][1]);
        const unsigned C0 = pkbf(sc[sub][2], sc[sub][3]);
        const unsigned B0 = pkbf(sc[sub][4], sc[sub][5]);
        const unsigned D0 = pkbf(sc[sub][6], sc[sub][7]);
        const unsigned A1 = pkbf(sc[sub][8], sc[sub][9]);
        const unsigned C1 = pkbf(sc[sub][10], sc[sub][11]);
        const unsigned B1 = pkbf(sc[sub][12], sc[sub][13]);
        const unsigned D1 = pkbf(sc[sub][14], sc[sub][15]);
        const unsigned sA0 = (unsigned)__shfl_xor((int)A0, 32);
        const unsigned sB0 = (unsigned)__shfl_xor((int)B0, 32);
        const unsigned sC0 = (unsigned)__shfl_xor((int)C0, 32);
        const unsigned sD0 = (unsigned)__shfl_xor((int)D0, 32);
        const unsigned sA1 = (unsigned)__shfl_xor((int)A1, 32);
        const unsigned sB1 = (unsigned)__shfl_xor((int)B1, 32);
        const unsigned sC1 = (unsigned)__shfl_xor((int)C1, 32);
        const unsigned sD1 = (unsigned)__shfl_xor((int)D1, 32);
        union { unsigned u[4]; bf16x8 v; } f0, f1;
        f0.u[0] = hi ? sB0 : A0;
        f0.u[1] = hi ? sD0 : C0;
        f0.u[2] = hi ? B0 : sA0;
        f0.u[3] = hi ? D0 : sC0;
        f1.u[0] = hi ? sB1 : A1;
        f1.u[1] = hi ? sD1 : C1;
        f1.u[2] = hi ? B1 : sA1;
        f1.u[3] = hi ? D1 : sC1;
        pa[sub * 2 + 0] = f0.v;
        pa[sub * 2 + 1] = f1.v;
      }
#pragma unroll
      for (int db = 0; db < 4; ++db) {
        const int vrow = db * 32 + ql;
#pragma unroll
        for (int ks = 0; ks < 4; ++ks) {
          const int chh = (ks * 2 + hi) ^ (ql & 7);
          bf16x8 bv = *reinterpret_cast<const bf16x8*>(&Vs[cur][vrow * 64 + chh * 8]);
          accO[db] = __builtin_amdgcn_mfma_f32_32x32x16_bf16(pa[ks], bv, accO[db], 0, 0, 0);
        }
      }
    }
    asm volatile("s_waitcnt vmcnt(0)");
    __syncthreads();
    cur ^= 1;
  }
  const float il = 1.0f / lsum;
#pragma unroll
  for (int r = 0; r < 16; ++r) {
    const int rb = (r & 3) + 8 * (r >> 2);
    const float ir = __shfl(il, rb + 4 * hi);
    const int qrow = q0 + rb + 4 * hi;
#pragma unroll
    for (int db = 0; db < 4; ++db)
      o[(size_t)qrow * HID + h * HDIM + db * 32 + ql] = f2bf(accO[db][r] * ir);
  }
}

// ----------------------------------------------------------------
extern "C" void kernel_launch(void* const* d_in, const int* in_sizes, int n_in,
                              void* d_out, int out_size, void* d_ws, size_t ws_size,
                              hipStream_t stream) {
  (void)in_sizes; (void)n_in; (void)out_size; (void)ws_size;
  const float* x  = (const float*)d_in[0];
  const float* Wq = (const float*)d_in[1];
  const float* Wk = (const float*)d_in[2];
  const float* Wv = (const float*)d_in[3];
  const float* Wo = (const float*)d_in[4];
  const float* Aq = (const float*)d_in[5];
  const float* Bq = (const float*)d_in[6];
  const float* Ak = (const float*)d_in[7];
  const float* Bk = (const float*)d_in[8];
  const float* Av = (const float*)d_in[9];
  const float* Bv = (const float*)d_in[10];
  float* out = (float*)d_out;

  char* p = (char*)d_ws;
  __hip_bfloat16* xb   = (__hip_bfloat16*)p; p += (size_t)SEQ * HID * 2;       // reused as ab
  __hip_bfloat16* wqkv = (__hip_bfloat16*)p; p += (size_t)3 * HID * HID * 2;   // [0:32M] reused for Wo
  __hip_bfloat16* qb   = (__hip_bfloat16*)p; p += (size_t)SEQ * HID * 2;
  __hip_bfloat16* kb   = (__hip_bfloat16*)p; p += (size_t)SEQ * HID * 2;
  __hip_bfloat16* vb   = (__hip_bfloat16*)p; p += (size_t)SEQ * HID * 2;
  __hip_bfloat16* vtb  = (__hip_bfloat16*)p; p += (size_t)SEQ * HID * 2;
  float* tq   = (float*)p; p += SEQ * LR * 4;
  float* tk   = (float*)p; p += SEQ * LR * 4;
  float* tv   = (float*)p; p += SEQ * LR * 4;
  float* cosb = (float*)p; p += SEQ * 64 * 4;
  float* sinb = (float*)p; p += SEQ * 64 * 4;
  __hip_bfloat16* ab = xb;  // x no longer needed after QKV GEMMs

  conv_f32_bf16<<<SEQ * HID / 1024, 256, 0, stream>>>(x, xb, SEQ * HID / 4);
  lora_t<<<SEQ * 3 / 4, 256, 0, stream>>>(x, Aq, Ak, Av, tq, tk, tv);
  rope_tables<<<SEQ * 64 / 256, 256, 0, stream>>>(cosb, sinb);
  conv_f32_bf16<<<HID * HID / 1024, 256, 0, stream>>>(Wq, wqkv + 0 * (size_t)HID * HID, HID * HID / 4);
  conv_f32_bf16<<<HID * HID / 1024, 256, 0, stream>>>(Wk, wqkv + 1 * (size_t)HID * HID, HID * HID / 4);
  conv_f32_bf16<<<HID * HID / 1024, 256, 0, stream>>>(Wv, wqkv + 2 * (size_t)HID * HID, HID * HID / 4);

  gemm3<true><<<dim3(16, 8, 3), 512, 0, stream>>>(xb, wqkv, tq, tk, tv, Bq, Bk, Bv,
                                                  qb, kb, vb, nullptr);

  rope_apply<<<SEQ * NHEADS * 64 / 256, 256, 0, stream>>>(qb, cosb, sinb);
  rope_apply<<<SEQ * NHEADS * 64 / 256, 256, 0, stream>>>(kb, cosb, sinb);
  transpose_v<<<dim3(SEQ / 64, HDIM / 64, NHEADS), 256, 0, stream>>>(vb, vtb);
  flash_attn4<<<512, 256, 0, stream>>>(qb, kb, vtb, ab);

  conv_f32_bf16<<<HID * HID / 1024, 256, 0, stream>>>(Wo, wqkv, HID * HID / 4);
  gemm2o<<<dim3(16, 16), 512, 0, stream>>>(ab, wqkv, out);
}

// Round 10
// 517.640 us; speedup vs baseline: 1.5332x; 1.1111x over previous
//
#include <hip/hip_runtime.h>
#include <hip/hip_bf16.h>

#define SEQ 2048
#define HID 4096
#define NHEADS 32
#define HDIM 128
#define LR 8

typedef __attribute__((ext_vector_type(8))) short bf16x8;
typedef __attribute__((ext_vector_type(4))) float f32x4;
typedef __attribute__((ext_vector_type(16))) float f32x16;

typedef __attribute__((address_space(3))) void lds_void;
typedef const __attribute__((address_space(1))) void glb_void;

static __device__ __forceinline__ float bf2f(__hip_bfloat16 v) { return __bfloat162float(v); }
static __device__ __forceinline__ __hip_bfloat16 f2bf(float v) { return __float2bfloat16(v); }

static __device__ __forceinline__ unsigned pkbf(float lo, float hi2) {
  __hip_bfloat16 l = __float2bfloat16(lo), h2 = __float2bfloat16(hi2);
  unsigned short ul = *reinterpret_cast<unsigned short*>(&l);
  unsigned short uh = *reinterpret_cast<unsigned short*>(&h2);
  return ((unsigned)uh << 16) | ul;
}

// ---------------------------------------------------------------- fp32 -> bf16
__global__ __launch_bounds__(256) void conv_f32_bf16(const float* __restrict__ src,
                                                     __hip_bfloat16* __restrict__ dst,
                                                     int n4) {
  const int i = blockIdx.x * 256 + threadIdx.x;
  if (i >= n4) return;
  const float4 v = reinterpret_cast<const float4*>(src)[i];
  union { __hip_bfloat16 h[4]; ushort4 u; } pk;
  pk.h[0] = f2bf(v.x); pk.h[1] = f2bf(v.y); pk.h[2] = f2bf(v.z); pk.h[3] = f2bf(v.w);
  reinterpret_cast<ushort4*>(dst)[i] = pk.u;
}

// ---------------------------------------------------------------- t = x @ A^T  (fp32, rank 8)
__global__ __launch_bounds__(256) void lora_t(const float* __restrict__ x,
                                              const float* __restrict__ Aq,
                                              const float* __restrict__ Ak,
                                              const float* __restrict__ Av,
                                              float* __restrict__ tq,
                                              float* __restrict__ tk,
                                              float* __restrict__ tv) {
  const int gw = blockIdx.x * 4 + (threadIdx.x >> 6);
  const int lane = threadIdx.x & 63;
  const int which = gw / SEQ;
  const int s = gw - which * SEQ;
  const float* A = (which == 0) ? Aq : (which == 1) ? Ak : Av;
  float* t = (which == 0) ? tq : (which == 1) ? tk : tv;
  float acc[LR];
#pragma unroll
  for (int r = 0; r < LR; ++r) acc[r] = 0.0f;
  const float4* xr = reinterpret_cast<const float4*>(x + (size_t)s * HID);
  for (int c = lane; c < HID / 4; c += 64) {
    const float4 xv = xr[c];
#pragma unroll
    for (int r = 0; r < LR; ++r) {
      const float4 av = reinterpret_cast<const float4*>(A + r * HID)[c];
      acc[r] += xv.x * av.x + xv.y * av.y + xv.z * av.z + xv.w * av.w;
    }
  }
#pragma unroll
  for (int r = 0; r < LR; ++r) {
    float vv = acc[r];
#pragma unroll
    for (int off = 32; off > 0; off >>= 1) vv += __shfl_down(vv, off);
    if (lane == 0) t[s * LR + r] = vv;
  }
}

// ---------------------------------------------------------------- RoPE cos/sin tables [S][64]
__global__ __launch_bounds__(256) void rope_tables(float* __restrict__ cosb,
                                                   float* __restrict__ sinb) {
  const int i = blockIdx.x * 256 + threadIdx.x;
  const int s = i >> 6, d = i & 63;
  const float invf = powf(10000.0f, -(float)d * (1.0f / 64.0f));
  const float ang = (float)s * invf;
  cosb[i] = cosf(ang);
  sinb[i] = sinf(ang);
}

// ---------------------------------------------------------------- RoPE in-place on bf16 (S,4096)
__global__ __launch_bounds__(256) void rope_apply(__hip_bfloat16* __restrict__ t,
                                                  const float* __restrict__ cosb,
                                                  const float* __restrict__ sinb) {
  const int i = blockIdx.x * 256 + threadIdx.x;
  const int d = i & 63;
  const int hh = (i >> 6) & (NHEADS - 1);
  const int s = i >> 11;
  const size_t base = (size_t)s * HID + hh * HDIM;
  const float x1 = bf2f(t[base + d]);
  const float x2 = bf2f(t[base + d + 64]);
  const float cc = cosb[s * 64 + d];
  const float ss = sinb[s * 64 + d];
  t[base + d] = f2bf(x1 * cc - x2 * ss);
  t[base + d + 64] = f2bf(x1 * ss + x2 * cc);
}

// ---------------------------------------------------------------- V (S,4096) -> Vt [h][d][s]
__global__ __launch_bounds__(256) void transpose_v(const __hip_bfloat16* __restrict__ v,
                                                   __hip_bfloat16* __restrict__ vt) {
  __shared__ __hip_bfloat16 tile[64][72];
  const int h = blockIdx.z;
  const int s0 = blockIdx.x * 64;
  const int db = blockIdx.y * 64;
  const int c = (threadIdx.x & 7) * 8;
  const int r = threadIdx.x >> 3;
#pragma unroll
  for (int p = 0; p < 2; ++p) {
    const int rr = r + p * 32;
    *reinterpret_cast<float4*>(&tile[rr][c]) =
        *reinterpret_cast<const float4*>(v + (size_t)(s0 + rr) * HID + h * HDIM + db + c);
  }
  __syncthreads();
#pragma unroll
  for (int p = 0; p < 2; ++p) {
    const int rr = r + p * 32;
    alignas(16) __hip_bfloat16 tmp[8];
#pragma unroll
    for (int j = 0; j < 8; ++j) tmp[j] = tile[c + j][rr];
    *reinterpret_cast<float4*>(vt + (size_t)(h * HDIM + db + rr) * SEQ + s0 + c) =
        *reinterpret_cast<float4*>(tmp);
  }
}

// ---------------------------------------------------------------- counted-vmcnt GEMM, BM=128 BN=256 BK=64
// R10: 3-deep prefetch (T4 depth). 3 LDS buffers (144 KB), stage tile j+2 while
// computing tile j. Per-wave issue order per tile: [kh0 x3, kh1 x3]; entering any
// phase outstanding = 12, s_waitcnt vmcnt(9) retires exactly the kh-plane being
// read. ~4 phases of HBM-latency cover vs R7's 1. Rest identical to R7 (T2
// both-sides swizzle, XCD col-panel L2 mapping, 768-block balanced grid).
template <bool LORA>
__global__ __launch_bounds__(512, 2) void gemm2(const __hip_bfloat16* __restrict__ X,
                                                const __hip_bfloat16* __restrict__ wqkv,
                                                const float* __restrict__ tq,
                                                const float* __restrict__ tk,
                                                const float* __restrict__ tv,
                                                const float* __restrict__ Bq,
                                                const float* __restrict__ Bk,
                                                const float* __restrict__ Bv,
                                                __hip_bfloat16* __restrict__ qb,
                                                __hip_bfloat16* __restrict__ kb,
                                                __hip_bfloat16* __restrict__ vb,
                                                float* __restrict__ outf) {
  __shared__ __hip_bfloat16 Al[3][2][128][32];  // 48 KB
  __shared__ __hip_bfloat16 Bl[3][2][256][32];  // 96 KB
  const int z = blockIdx.z;
  const __hip_bfloat16* W = wqkv + (size_t)z * HID * HID;
  const float* T = (z == 0) ? tq : (z == 1) ? tk : tv;
  const float* BL = (z == 0) ? Bq : (z == 1) ? Bk : Bv;
  __hip_bfloat16* outb = (z == 0) ? qb : (z == 1) ? kb : vb;

  const int tid = threadIdx.x;
  const int lane = tid & 63;
  const int w = tid >> 6;   // 0..7
  const int wm = w >> 2;    // 0..1
  const int wn = w & 3;     // 0..3
  const int g = lane >> 4, lr = lane & 15;

  // XCD col-panel swizzle: xcd owns col panels {2x,2x+1} = 4MB of W (L2-resident)
  const int fid = blockIdx.x + (blockIdx.y << 4);
  const int xcd = fid & 7;
  const int j8 = fid >> 3;
  const int rowBase = (j8 >> 1) * 128;
  const int colBase = (xcd * 2 + (j8 & 1)) * 256;

  const int sA = w * 64 + lane;
  const int rA = sA >> 2, cA = sA & 3;
  const __hip_bfloat16* Ag = X + (size_t)(rowBase + rA) * HID + ((cA ^ ((rA >> 1) & 3)) * 8);
  const int sB0 = (w * 2) * 64 + lane;
  const int sB1 = (w * 2 + 1) * 64 + lane;
  const int rB0 = sB0 >> 2, cB0 = sB0 & 3;
  const int rB1 = sB1 >> 2, cB1 = sB1 & 3;
  const __hip_bfloat16* Bg0 = W + (size_t)(colBase + rB0) * HID + ((cB0 ^ ((rB0 >> 1) & 3)) * 8);
  const __hip_bfloat16* Bg1 = W + (size_t)(colBase + rB1) * HID + ((cB1 ^ ((rB1 >> 1) & 3)) * 8);

#define STG2(buf_, kh_, kk_)                                                        \
  do {                                                                              \
    __builtin_amdgcn_global_load_lds((glb_void*)(Ag + (kk_) + (kh_) * 32),          \
        (lds_void*)(&Al[buf_][kh_][0][0] + w * 512), 16, 0, 0);                     \
    __builtin_amdgcn_global_load_lds((glb_void*)(Bg0 + (kk_) + (kh_) * 32),         \
        (lds_void*)(&Bl[buf_][kh_][0][0] + (w * 2) * 512), 16, 0, 0);               \
    __builtin_amdgcn_global_load_lds((glb_void*)(Bg1 + (kk_) + (kh_) * 32),         \
        (lds_void*)(&Bl[buf_][kh_][0][0] + (w * 2 + 1) * 512), 16, 0, 0);           \
  } while (0)

  f32x4 acc[4][4];
#pragma unroll
  for (int m = 0; m < 4; ++m)
#pragma unroll
    for (int n = 0; n < 4; ++n)
#pragma unroll
      for (int e = 0; e < 4; ++e) acc[m][n][e] = 0.0f;

  const int ch = (g ^ ((lr >> 1) & 3)) * 8;

  // prologue: tiles 0 and 1, FIFO [T0kh0, T0kh1, T1kh0, T1kh1] -> 12 outstanding
  STG2(0, 0, 0);
  __builtin_amdgcn_sched_barrier(0);
  STG2(0, 1, 0);
  __builtin_amdgcn_sched_barrier(0);
  STG2(1, 0, 64);
  __builtin_amdgcn_sched_barrier(0);
  STG2(1, 1, 64);

  int bcur = 0;
  for (int j = 0; j < 64; ++j) {
    int bn2 = bcur + 2; if (bn2 >= 3) bn2 -= 3;   // (j+2) % 3
    const int kn = (j < 62 ? j + 2 : 63) * 64;    // tail: redundant re-stage keeps FIFO
#pragma unroll
    for (int kh = 0; kh < 2; ++kh) {
      asm volatile("s_waitcnt vmcnt(9) lgkmcnt(0)" ::: "memory");
      __builtin_amdgcn_s_barrier();
      __builtin_amdgcn_sched_barrier(0);
      bf16x8 af[4], bfr[4];
#pragma unroll
      for (int m = 0; m < 4; ++m)
        af[m] = *reinterpret_cast<const bf16x8*>(&Al[bcur][kh][wm * 64 + m * 16 + lr][ch]);
#pragma unroll
      for (int n = 0; n < 4; ++n)
        bfr[n] = *reinterpret_cast<const bf16x8*>(&Bl[bcur][kh][wn * 64 + n * 16 + lr][ch]);
      if (kh == 0) STG2(bn2, 0, kn); else STG2(bn2, 1, kn);
      __builtin_amdgcn_sched_barrier(0);
      __builtin_amdgcn_s_setprio(1);
#pragma unroll
      for (int m = 0; m < 4; ++m)
#pragma unroll
        for (int n = 0; n < 4; ++n)
          acc[m][n] = __builtin_amdgcn_mfma_f32_16x16x32_bf16(af[m], bfr[n], acc[m][n], 0, 0, 0);
      __builtin_amdgcn_s_setprio(0);
    }
    ++bcur; if (bcur == 3) bcur = 0;
  }
#undef STG2

  const int orow0 = rowBase + wm * 64 + g * 4;
  const int ocol0 = colBase + wn * 64 + lr;
  if constexpr (LORA) {
    float bl[4][8];
#pragma unroll
    for (int n = 0; n < 4; ++n) {
      const int cc = ocol0 + n * 16;
      const int fc = (cc < HID / 2) ? (2 * cc) : (2 * (cc - HID / 2) + 1);
#pragma unroll
      for (int e = 0; e < 8; ++e) bl[n][e] = BL[fc * LR + e];
    }
#pragma unroll
    for (int m = 0; m < 4; ++m) {
      float tr[4][8];
#pragma unroll
      for (int r2 = 0; r2 < 4; ++r2)
#pragma unroll
        for (int e = 0; e < 8; ++e) tr[r2][e] = T[(size_t)(orow0 + m * 16 + r2) * LR + e];
#pragma unroll
      for (int n = 0; n < 4; ++n)
#pragma unroll
        for (int r2 = 0; r2 < 4; ++r2) {
          float dot = 0.0f;
#pragma unroll
          for (int e = 0; e < 8; ++e) dot += tr[r2][e] * bl[n][e];
          outb[(size_t)(orow0 + m * 16 + r2) * HID + ocol0 + n * 16] =
              f2bf(acc[m][n][r2] + 2.0f * dot);
        }
    }
  } else {
#pragma unroll
    for (int m = 0; m < 4; ++m)
#pragma unroll
      for (int n = 0; n < 4; ++n)
#pragma unroll
        for (int r2 = 0; r2 < 4; ++r2)
          outf[(size_t)(orow0 + m * 16 + r2) * HID + ocol0 + n * 16] = acc[m][n][r2];
  }
}

// ---------------------------------------------------------------- causal flash attention v4
#define STAGE(buf_, kvb_)                                                                   \
  do {                                                                                      \
    _Pragma("unroll") for (int i_ = 0; i_ < 4; ++i_) {                                      \
      const int sb_ = (w * 4 + i_) * 64;                                                    \
      {                                                                                     \
        const int slot_ = sb_ + lane;                                                       \
        const int rr_ = slot_ >> 4, cc_ = slot_ & 15;                                       \
        __builtin_amdgcn_global_load_lds(                                                   \
            (glb_void*)(kg + (size_t)((kvb_) + rr_) * HID + h * HDIM +                      \
                        ((cc_ ^ (rr_ & 15)) << 3)),                                         \
            (lds_void*)(&Ks[buf_][sb_ * 8]), 16, 0, 0);                                     \
      }                                                                                     \
      {                                                                                     \
        const int slot_ = sb_ + lane;                                                       \
        const int rr_ = slot_ >> 3, cc_ = slot_ & 7;                                        \
        __builtin_amdgcn_global_load_lds(                                                   \
            (glb_void*)(vt + ((size_t)h * HDIM + rr_) * SEQ + (kvb_) +                      \
                        ((cc_ ^ (rr_ & 7)) << 3)),                                          \
            (lds_void*)(&Vs[buf_][sb_ * 8]), 16, 0, 0);                                     \
      }                                                                                     \
    }                                                                                       \
  } while (0)

__global__ __launch_bounds__(256, 2) void flash_attn4(const __hip_bfloat16* __restrict__ qg,
                                                      const __hip_bfloat16* __restrict__ kg,
                                                      const __hip_bfloat16* __restrict__ vt,
                                                      __hip_bfloat16* __restrict__ o) {
  __shared__ __hip_bfloat16 Ks[2][64 * 128];
  __shared__ __hip_bfloat16 Vs[2][128 * 64];
  const int tid = threadIdx.x;
  const int lane = tid & 63;
  const int w = tid >> 6;
  const int ql = lane & 31;
  const int hi = lane >> 5;
  const int bx = blockIdx.x;
  const int h = bx & 31;
  const int strip = (bx < 256) ? (bx >> 5) : (15 - ((bx - 256) >> 5));
  const float scale = 0.088388347648318447f;

  const int q0 = strip * 128 + w * 32;
  const int nt = 2 * strip + 2;
  const int qgl = q0 + ql;

  bf16x8 bq[8];
#pragma unroll
  for (int sl = 0; sl < 8; ++sl)
    bq[sl] = *reinterpret_cast<const bf16x8*>(qg + (size_t)qgl * HID + h * HDIM + sl * 16 + hi * 8);

  f32x16 accO[4];
#pragma unroll
  for (int db = 0; db < 4; ++db)
#pragma unroll
    for (int e = 0; e < 16; ++e) accO[db][e] = 0.0f;
  float m_run = -1e30f, lsum = 0.0f;

  int cur = 0;
  STAGE(0, 0);
  asm volatile("s_waitcnt vmcnt(0)");
  __syncthreads();

  for (int t = 0; t < nt; ++t) {
    const int kvb = t * 64;
    if (t + 1 < nt) STAGE(cur ^ 1, (t + 1) * 64);
    if (kvb <= q0 + 31) {
      f32x16 sc[2];
#pragma unroll
      for (int sub = 0; sub < 2; ++sub) {
#pragma unroll
        for (int e = 0; e < 16; ++e) sc[sub][e] = 0.0f;
        const int krow = sub * 32 + ql;
#pragma unroll
        for (int sl = 0; sl < 8; ++sl) {
          const int chh = (sl * 2 + hi) ^ (ql & 15);
          bf16x8 ak = *reinterpret_cast<const bf16x8*>(&Ks[cur][krow * 128 + chh * 8]);
          sc[sub] = __builtin_amdgcn_mfma_f32_32x32x16_bf16(ak, bq[sl], sc[sub], 0, 0, 0);
        }
      }
      float smax = -3.0e38f;
      if (kvb + 63 > q0) {
#pragma unroll
        for (int sub = 0; sub < 2; ++sub)
#pragma unroll
          for (int r = 0; r < 16; ++r) {
            const int kvg = kvb + sub * 32 + (r & 3) + 8 * (r >> 2) + 4 * hi;
            float v2 = sc[sub][r] * scale;
            v2 = (kvg > qgl) ? -3.0e38f : v2;
            sc[sub][r] = v2;
            smax = fmaxf(smax, v2);
          }
      } else {
#pragma unroll
        for (int sub = 0; sub < 2; ++sub)
#pragma unroll
          for (int r = 0; r < 16; ++r) {
            const float v2 = sc[sub][r] * scale;
            sc[sub][r] = v2;
            smax = fmaxf(smax, v2);
          }
      }
      smax = fmaxf(smax, __shfl_xor(smax, 32));
      if (__any(smax > m_run + 8.0f)) {
        const float mnew = fmaxf(m_run, smax);
        const float sca = __expf(m_run - mnew);
        m_run = mnew;
        lsum *= sca;
#pragma unroll
        for (int r = 0; r < 16; ++r) {
          const float sr = __shfl(sca, (r & 3) + 8 * (r >> 2) + 4 * hi);
#pragma unroll
          for (int db = 0; db < 4; ++db) accO[db][r] *= sr;
        }
      }
      float psum = 0.0f;
#pragma unroll
      for (int sub = 0; sub < 2; ++sub)
#pragma unroll
        for (int r = 0; r < 16; ++r) {
          const float p = __expf(sc[sub][r] - m_run);
          sc[sub][r] = p;
          psum += p;
        }
      psum += __shfl_xor(psum, 32);
      lsum += psum;
      bf16x8 pa[4];
#pragma unroll
      for (int sub = 0; sub < 2; ++sub) {
        const unsigned A0 = pkbf(sc[sub][0], sc[sub][1]);
        const unsigned C0 = pkbf(sc[sub][2], sc[sub][3]);
        const unsigned B0 = pkbf(sc[sub][4], sc[sub][5]);
        const unsigned D0 = pkbf(sc[sub][6], sc[sub][7]);
        const unsigned A1 = pkbf(sc[sub][8], sc[sub][9]);
        const unsigned C1 = pkbf(sc[sub][10], sc[sub][11]);
        const unsigned B1 = pkbf(sc[sub][12], sc[sub][13]);
        const unsigned D1 = pkbf(sc[sub][14], sc[sub][15]);
        const unsigned sA0 = (unsigned)__shfl_xor((int)A0, 32);
        const unsigned sB0 = (unsigned)__shfl_xor((int)B0, 32);
        const unsigned sC0 = (unsigned)__shfl_xor((int)C0, 32);
        const unsigned sD0 = (unsigned)__shfl_xor((int)D0, 32);
        const unsigned sA1 = (unsigned)__shfl_xor((int)A1, 32);
        const unsigned sB1 = (unsigned)__shfl_xor((int)B1, 32);
        const unsigned sC1 = (unsigned)__shfl_xor((int)C1, 32);
        const unsigned sD1 = (unsigned)__shfl_xor((int)D1, 32);
        union { unsigned u[4]; bf16x8 v; } f0, f1;
        f0.u[0] = hi ? sB0 : A0;
        f0.u[1] = hi ? sD0 : C0;
        f0.u[2] = hi ? B0 : sA0;
        f0.u[3] = hi ? D0 : sC0;
        f1.u[0] = hi ? sB1 : A1;
        f1.u[1] = hi ? sD1 : C1;
        f1.u[2] = hi ? B1 : sA1;
        f1.u[3] = hi ? D1 : sC1;
        pa[sub * 2 + 0] = f0.v;
        pa[sub * 2 + 1] = f1.v;
      }
#pragma unroll
      for (int db = 0; db < 4; ++db) {
        const int vrow = db * 32 + ql;
#pragma unroll
        for (int ks = 0; ks < 4; ++ks) {
          const int chh = (ks * 2 + hi) ^ (ql & 7);
          bf16x8 bv = *reinterpret_cast<const bf16x8*>(&Vs[cur][vrow * 64 + chh * 8]);
          accO[db] = __builtin_amdgcn_mfma_f32_32x32x16_bf16(pa[ks], bv, accO[db], 0, 0, 0);
        }
      }
    }
    asm volatile("s_waitcnt vmcnt(0)");
    __syncthreads();
    cur ^= 1;
  }
  const float il = 1.0f / lsum;
#pragma unroll
  for (int r = 0; r < 16; ++r) {
    const int rb = (r & 3) + 8 * (r >> 2);
    const float ir = __shfl(il, rb + 4 * hi);
    const int qrow = q0 + rb + 4 * hi;
#pragma unroll
    for (int db = 0; db < 4; ++db)
      o[(size_t)qrow * HID + h * HDIM + db * 32 + ql] = f2bf(accO[db][r] * ir);
  }
}

// ----------------------------------------------------------------
extern "C" void kernel_launch(void* const* d_in, const int* in_sizes, int n_in,
                              void* d_out, int out_size, void* d_ws, size_t ws_size,
                              hipStream_t stream) {
  (void)in_sizes; (void)n_in; (void)out_size; (void)ws_size;
  const float* x  = (const float*)d_in[0];
  const float* Wq = (const float*)d_in[1];
  const float* Wk = (const float*)d_in[2];
  const float* Wv = (const float*)d_in[3];
  const float* Wo = (const float*)d_in[4];
  const float* Aq = (const float*)d_in[5];
  const float* Bq = (const float*)d_in[6];
  const float* Ak = (const float*)d_in[7];
  const float* Bk = (const float*)d_in[8];
  const float* Av = (const float*)d_in[9];
  const float* Bv = (const float*)d_in[10];
  float* out = (float*)d_out;

  char* p = (char*)d_ws;
  __hip_bfloat16* xb   = (__hip_bfloat16*)p; p += (size_t)SEQ * HID * 2;       // reused as ab
  __hip_bfloat16* wqkv = (__hip_bfloat16*)p; p += (size_t)3 * HID * HID * 2;   // [0:32M] reused for Wo
  __hip_bfloat16* qb   = (__hip_bfloat16*)p; p += (size_t)SEQ * HID * 2;
  __hip_bfloat16* kb   = (__hip_bfloat16*)p; p += (size_t)SEQ * HID * 2;
  __hip_bfloat16* vb   = (__hip_bfloat16*)p; p += (size_t)SEQ * HID * 2;
  __hip_bfloat16* vtb  = (__hip_bfloat16*)p; p += (size_t)SEQ * HID * 2;
  float* tq   = (float*)p; p += SEQ * LR * 4;
  float* tk   = (float*)p; p += SEQ * LR * 4;
  float* tv   = (float*)p; p += SEQ * LR * 4;
  float* cosb = (float*)p; p += SEQ * 64 * 4;
  float* sinb = (float*)p; p += SEQ * 64 * 4;
  __hip_bfloat16* ab = xb;  // x no longer needed after QKV GEMMs

  conv_f32_bf16<<<SEQ * HID / 1024, 256, 0, stream>>>(x, xb, SEQ * HID / 4);
  lora_t<<<SEQ * 3 / 4, 256, 0, stream>>>(x, Aq, Ak, Av, tq, tk, tv);
  rope_tables<<<SEQ * 64 / 256, 256, 0, stream>>>(cosb, sinb);
  conv_f32_bf16<<<HID * HID / 1024, 256, 0, stream>>>(Wq, wqkv + 0 * (size_t)HID * HID, HID * HID / 4);
  conv_f32_bf16<<<HID * HID / 1024, 256, 0, stream>>>(Wk, wqkv + 1 * (size_t)HID * HID, HID * HID / 4);
  conv_f32_bf16<<<HID * HID / 1024, 256, 0, stream>>>(Wv, wqkv + 2 * (size_t)HID * HID, HID * HID / 4);

  gemm2<true><<<dim3(16, 16, 3), 512, 0, stream>>>(xb, wqkv, tq, tk, tv, Bq, Bk, Bv,
                                                   qb, kb, vb, nullptr);

  rope_apply<<<SEQ * NHEADS * 64 / 256, 256, 0, stream>>>(qb, cosb, sinb);
  rope_apply<<<SEQ * NHEADS * 64 / 256, 256, 0, stream>>>(kb, cosb, sinb);
  transpose_v<<<dim3(SEQ / 64, HDIM / 64, NHEADS), 256, 0, stream>>>(vb, vtb);
  flash_attn4<<<512, 256, 0, stream>>>(qb, kb, vtb, ab);

  conv_f32_bf16<<<HID * HID / 1024, 256, 0, stream>>>(Wo, wqkv, HID * HID / 4);
  gemm2<false><<<dim3(16, 16, 1), 512, 0, stream>>>(ab, wqkv, nullptr, nullptr, nullptr,
                                                    nullptr, nullptr, nullptr,
                                                    nullptr, nullptr, nullptr, out);
}